// Round 2
// baseline (1050.916 us; speedup 1.0000x reference)
//
#include <hip/hip_runtime.h>

#define ARTIST_V 16384
#define GENRE_V  2048
#define TOTAL    18433
#define HIDDEN   9216
#define OUT_D    64
#define BATCH    4096

typedef unsigned int  uint;
typedef unsigned short ushort;
typedef __attribute__((ext_vector_type(8))) short short8;
typedef __attribute__((ext_vector_type(4))) float f32x4;

__device__ __forceinline__ ushort f2bf(float f) {
    uint u = __float_as_uint(f);
    u += 0x7FFFu + ((u >> 16) & 1u);      // RNE
    return (ushort)(u >> 16);
}
__device__ __forceinline__ float bf2f(ushort b) {
    return __uint_as_float(((uint)b) << 16);
}

// ---------------------------------------------------------------------------
// Phase 0: out[b][o] = b2[o]   (d_out is poisoned 0xAA before every launch)
// grid 256 x 256 threads, float4 stores
__global__ __launch_bounds__(256) void k_init(const float* __restrict__ b2,
                                              float4* __restrict__ out4) {
    int idx = blockIdx.x * 256 + threadIdx.x;          // 0..65535 float4s
    const float4* b24 = (const float4*)b2;             // 16 float4 per row
    out4[idx] = b24[threadIdx.x & 15];                 // (idx%16)==(tid%16)
}

// ---------------------------------------------------------------------------
// Phase 1: H2[h/8][b][e] = bf16(relu(W1[h,a_b] + W1[h,16384+g_b] + y_b*W1[h,18432] + b1[h]))
// One workgroup per 8-row h-block. Each row staged to LDS as bf16, gathered by all b.
__global__ __launch_bounds__(256) void k_hidden(
    const int*   __restrict__ artist,
    const int*   __restrict__ genre,
    const float* __restrict__ year,
    const float* __restrict__ W1,
    const float* __restrict__ b1,
    uint4*       __restrict__ H2v)
{
    __shared__ ushort srow[TOTAL + 4];                 // bf16 row (+ alignment shift)
    const int tid = threadIdx.x;
    const int hb  = blockIdx.x;                        // 0..1151
    const int h0  = hb * 8;

    uint res[16][4];
    #pragma unroll
    for (int j = 0; j < 16; j++) {
        res[j][0] = 0u; res[j][1] = 0u; res[j][2] = 0u; res[j][3] = 0u;
    }

    #pragma unroll
    for (int r = 0; r < 8; r++) {
        const int h = h0 + r;
        const size_t base = (size_t)h * TOTAL;
        const int t = (int)(base & 3);                 // LDS index shift so vec writes are 8B-aligned
        const int s = (4 - t) & 3;                     // scalar head elements until 16B-aligned source

        if (tid < s) srow[tid + t] = f2bf(W1[base + tid]);
        const int nvec = (TOTAL - s) >> 2;
        const float4* vp = (const float4*)(W1 + base + s);
        for (int j = tid; j < nvec; j += 256) {
            float4 v = vp[j];
            int o = s + t + 4 * j;                     // multiple of 4 -> byte offset %8==0
            uint2 packed;
            packed.x = (uint)f2bf(v.x) | ((uint)f2bf(v.y) << 16);
            packed.y = (uint)f2bf(v.z) | ((uint)f2bf(v.w) << 16);
            *(uint2*)(srow + o) = packed;
        }
        const int tail0 = s + 4 * nvec;
        const int ntail = TOTAL - tail0;               // 0..3
        if (tid < ntail) srow[t + tail0 + tid] = f2bf(W1[base + tail0 + tid]);
        __syncthreads();

        const float yc  = bf2f(srow[t + TOTAL - 1]);   // year weight column
        const float b1h = b1[h];
        #pragma unroll
        for (int j = 0; j < 16; j++) {
            int b = tid + 256 * j;
            int a = artist[b];
            int g = genre[b];
            float y = year[b];
            float hv = bf2f(srow[t + a]) + bf2f(srow[t + ARTIST_V + g]) + y * yc + b1h;
            hv = fmaxf(hv, 0.0f);
            res[j][r >> 1] |= ((uint)f2bf(hv)) << ((r & 1) * 16);
        }
        __syncthreads();                               // before next row overwrites srow
    }

    const size_t obase = (size_t)hb * BATCH;           // uint4 units
    #pragma unroll
    for (int j = 0; j < 16; j++) {
        int b = tid + 256 * j;
        uint4 v;
        v.x = res[j][0]; v.y = res[j][1]; v.z = res[j][2]; v.w = res[j][3];
        H2v[obase + b] = v;                            // 16B/lane coalesced
    }
}

// ---------------------------------------------------------------------------
// Phase 2: out[b][o] += sum_k H[b][k] * W2[o][k]   (bf16 MFMA, fp32 accum)
// grid (64 M-tiles, 18 K-splits) x 256 threads; wave w owns rows m0+16w..+15, all 64 cols.
__global__ __launch_bounds__(256) void k_gemm(
    const uint4* __restrict__ H2v,
    const float* __restrict__ W2,
    float*       __restrict__ out)
{
    const int lane = threadIdx.x & 63;
    const int wv   = threadIdx.x >> 6;
    const int l15  = lane & 15;
    const int lhi  = lane >> 4;
    const int m0   = blockIdx.x * 64 + wv * 16;
    const int k0   = blockIdx.y * 512;

    f32x4 acc[4];
    #pragma unroll
    for (int n = 0; n < 4; n++) acc[n] = (f32x4){0.f, 0.f, 0.f, 0.f};

    for (int k = k0; k < k0 + 512; k += 32) {
        // A fragment: lane holds H[b=m0+l15][k+8*lhi .. +8) = one dwordx4 from H2
        uint4 av = H2v[(size_t)((k >> 3) + lhi) * BATCH + (m0 + l15)];
        union { uint4 u; short8 s; } ua; ua.u = av;
        short8 afrag = ua.s;

        const float* wbase = W2 + (size_t)l15 * HIDDEN + (k + lhi * 8);
        #pragma unroll
        for (int n = 0; n < 4; n++) {
            const float* wp = wbase + (size_t)(n * 16) * HIDDEN;   // o = n*16 + l15
            float4 w0 = *(const float4*)wp;
            float4 w1 = *(const float4*)(wp + 4);
            short8 bfrag;
            bfrag[0] = (short)f2bf(w0.x); bfrag[1] = (short)f2bf(w0.y);
            bfrag[2] = (short)f2bf(w0.z); bfrag[3] = (short)f2bf(w0.w);
            bfrag[4] = (short)f2bf(w1.x); bfrag[5] = (short)f2bf(w1.y);
            bfrag[6] = (short)f2bf(w1.z); bfrag[7] = (short)f2bf(w1.w);
            acc[n] = __builtin_amdgcn_mfma_f32_16x16x32_bf16(afrag, bfrag, acc[n], 0, 0, 0);
        }
    }

    // D layout: row = (lane>>4)*4 + reg, col = lane&15   [measured m89]
    #pragma unroll
    for (int n = 0; n < 4; n++) {
        #pragma unroll
        for (int r = 0; r < 4; r++) {
            int row = m0 + lhi * 4 + r;
            int col = n * 16 + l15;
            atomicAdd(&out[(size_t)row * OUT_D + col], acc[n][r]);
        }
    }
}

// ---------------------------------------------------------------------------
extern "C" void kernel_launch(void* const* d_in, const int* in_sizes, int n_in,
                              void* d_out, int out_size, void* d_ws, size_t ws_size,
                              hipStream_t stream) {
    const int*   artist = (const int*)d_in[0];
    const int*   genre  = (const int*)d_in[1];
    const float* year   = (const float*)d_in[2];
    const float* W1     = (const float*)d_in[3];
    const float* b1     = (const float*)d_in[4];
    const float* W2     = (const float*)d_in[5];
    const float* b2     = (const float*)d_in[6];
    float* out = (float*)d_out;
    uint4* H2v = (uint4*)d_ws;                 // (9216/8)*4096*16 B = 75.5 MB

    k_init  <<<256, 256, 0, stream>>>(b2, (float4*)out);
    k_hidden<<<1152, 256, 0, stream>>>(artist, genre, year, W1, b1, H2v);
    k_gemm  <<<dim3(64, 18), 256, 0, stream>>>((const uint4*)H2v, W2, out);
}

// Round 3
// 941.275 us; speedup vs baseline: 1.1165x; 1.1165x over previous
//
#include <hip/hip_runtime.h>

#define ARTIST_V 16384
#define GENRE_V  2048
#define TOTAL    18433
#define HIDDEN   9216
#define OUT_D    64
#define BATCH    4096

// k_hidden geometry
#define ROWS_PB  6                     // rows per block
#define NBLK     (HIDDEN / ROWS_PB)    // 1536 blocks = 6 exact waves over 256 CUs
#define THR      512
#define SEG      (TOTAL - 1)           // 18432 staged columns (year col read directly)
#define PF_N     (SEG / 4 / THR)       // 9 float4 per thread per row

// k_gemm geometry
#define KSPLIT   4
#define KCHUNK   (HIDDEN / KSPLIT)     // 2304 (72 k-steps of 32)

typedef unsigned int   uint;
typedef unsigned short ushort;
typedef __attribute__((ext_vector_type(8))) short short8;
typedef __attribute__((ext_vector_type(4))) float f32x4;

__device__ __forceinline__ ushort f2bf(float f) {
    uint u = __float_as_uint(f);
    u += 0x7FFFu + ((u >> 16) & 1u);   // RNE
    return (ushort)(u >> 16);
}
__device__ __forceinline__ float bf2f(ushort b) {
    return __uint_as_float(((uint)b) << 16);
}

// ---------------------------------------------------------------------------
// W2 fp32 -> bf16 row-major [64][9216]  (576 blocks x 256 thr x 4 elems)
__global__ __launch_bounds__(256) void k_prep(const float* __restrict__ W2,
                                              ushort* __restrict__ W2b) {
    int t = blockIdx.x * 256 + threadIdx.x;       // 0..147455
    float4 v = *(const float4*)(W2 + (size_t)t * 4);
    uint2 p;
    p.x = (uint)f2bf(v.x) | ((uint)f2bf(v.y) << 16);
    p.y = (uint)f2bf(v.z) | ((uint)f2bf(v.w) << 16);
    *(uint2*)(W2b + (size_t)t * 4) = p;
}

// ---------------------------------------------------------------------------
// H2p[h/2][b] = pack(bf16(relu(h_{2p})), bf16(relu(h_{2p+1})))
// Pipelined: prefetch row r+1 into registers while gathering row r from LDS.
__global__ __launch_bounds__(THR) void k_hidden(
    const int*   __restrict__ artist,
    const int*   __restrict__ genre,
    const float* __restrict__ year,
    const float* __restrict__ W1,
    const float* __restrict__ b1,
    uint*        __restrict__ H2p)
{
    __shared__ ushort srow[SEG];                  // 36,864 B -> 2 blocks/CU possible
    const int tid = threadIdx.x;
    const int hb  = blockIdx.x;
    const int h0  = hb * ROWS_PB;

    // hoist per-batch inputs (8 chunks of 512)
    uint  ag[8]; float yv[8];
    #pragma unroll
    for (int j = 0; j < 8; j++) {
        int b = tid + THR * j;
        ag[j] = (uint)artist[b] | ((uint)genre[b] << 16);
        yv[j] = year[b];
    }

    uint res[8][3];
    #pragma unroll
    for (int j = 0; j < 8; j++) { res[j][0] = 0u; res[j][1] = 0u; res[j][2] = 0u; }

    float4 pf[PF_N];
    {   // prefetch + stage row 0
        const float4* vp = (const float4*)(W1 + (size_t)h0 * TOTAL);
        #pragma unroll
        for (int i = 0; i < PF_N; i++) pf[i] = vp[i * THR + tid];
        #pragma unroll
        for (int i = 0; i < PF_N; i++) {
            uint2 p;
            p.x = (uint)f2bf(pf[i].x) | ((uint)f2bf(pf[i].y) << 16);
            p.y = (uint)f2bf(pf[i].z) | ((uint)f2bf(pf[i].w) << 16);
            *(uint2*)(srow + (i * THR + tid) * 4) = p;
        }
        __syncthreads();
    }

    #pragma unroll
    for (int r = 0; r < ROWS_PB; r++) {
        const int h = h0 + r;
        if (r + 1 < ROWS_PB) {                    // issue next row's loads EARLY
            const float4* vp = (const float4*)(W1 + (size_t)(h + 1) * TOTAL);
            #pragma unroll
            for (int i = 0; i < PF_N; i++) pf[i] = vp[i * THR + tid];
        }
        const float yw  = W1[(size_t)h * TOTAL + SEG];   // uniform scalar
        const float b1h = b1[h];
        #pragma unroll
        for (int j = 0; j < 8; j++) {             // gather row r (overlaps loads)
            int a = (int)(ag[j] & 0xFFFFu);
            int g = (int)(ag[j] >> 16);
            float hv = bf2f(srow[a]) + bf2f(srow[ARTIST_V + g]) + yv[j] * yw + b1h;
            hv = fmaxf(hv, 0.0f);
            res[j][r >> 1] |= ((uint)f2bf(hv)) << ((r & 1) * 16);
        }
        __syncthreads();                          // all gathers of row r done
        if (r + 1 < ROWS_PB) {                    // convert + write row r+1
            #pragma unroll
            for (int i = 0; i < PF_N; i++) {
                uint2 p;
                p.x = (uint)f2bf(pf[i].x) | ((uint)f2bf(pf[i].y) << 16);
                p.y = (uint)f2bf(pf[i].z) | ((uint)f2bf(pf[i].w) << 16);
                *(uint2*)(srow + (i * THR + tid) * 4) = p;
            }
            __syncthreads();
        }
    }

    #pragma unroll
    for (int q = 0; q < 3; q++) {                 // pair-row q of this block
        size_t base = (size_t)(hb * 3 + q) * BATCH;
        #pragma unroll
        for (int j = 0; j < 8; j++) H2p[base + tid + THR * j] = res[j][q];
    }
}

// ---------------------------------------------------------------------------
// part[split][b][o] = sum_{k in chunk} H[b][k] * W2[o][k]   (no atomics)
__global__ __launch_bounds__(256) void k_gemm(
    const uint*   __restrict__ H2p,
    const ushort* __restrict__ W2b,
    float*        __restrict__ part)
{
    const int lane = threadIdx.x & 63;
    const int wv   = threadIdx.x >> 6;
    const int l15  = lane & 15;
    const int lhi  = lane >> 4;
    const int m0   = blockIdx.x * 64 + wv * 16;
    const int k0   = blockIdx.y * KCHUNK;

    f32x4 acc[4];
    #pragma unroll
    for (int n = 0; n < 4; n++) acc[n] = (f32x4){0.f, 0.f, 0.f, 0.f};

    for (int kk = k0; kk < k0 + KCHUNK; kk += 32) {
        int p0 = (kk >> 1) + lhi * 4;
        union { uint u[4]; short8 s; } ua;
        #pragma unroll
        for (int q = 0; q < 4; q++)
            ua.u[q] = H2p[(size_t)(p0 + q) * BATCH + m0 + l15];
        short8 afrag = ua.s;

        const ushort* wb = W2b + (size_t)l15 * HIDDEN + kk + lhi * 8;
        #pragma unroll
        for (int n = 0; n < 4; n++) {
            short8 bfrag = *(const short8*)(wb + (size_t)(n * 16) * HIDDEN);
            acc[n] = __builtin_amdgcn_mfma_f32_16x16x32_bf16(afrag, bfrag, acc[n], 0, 0, 0);
        }
    }

    float* pb = part + (size_t)blockIdx.y * (BATCH * OUT_D);
    #pragma unroll
    for (int n = 0; n < 4; n++) {
        #pragma unroll
        for (int r = 0; r < 4; r++)
            pb[(size_t)(m0 + lhi * 4 + r) * OUT_D + n * 16 + l15] = acc[n][r];
    }
}

// ---------------------------------------------------------------------------
// out[b][o] = b2[o] + sum_splits part[s][b][o]    (256 blocks x 256 thr, float4)
__global__ __launch_bounds__(256) void k_reduce(const float* __restrict__ part,
                                                const float* __restrict__ b2,
                                                float4*      __restrict__ out4) {
    int idx = blockIdx.x * 256 + threadIdx.x;     // 0..65535 float4
    const float4* p = (const float4*)part;
    float4 s0 = p[idx];
    float4 s1 = p[idx + 65536];
    float4 s2 = p[idx + 131072];
    float4 s3 = p[idx + 196608];
    float4 bb = ((const float4*)b2)[threadIdx.x & 15];
    float4 o;
    o.x = s0.x + s1.x + s2.x + s3.x + bb.x;
    o.y = s0.y + s1.y + s2.y + s3.y + bb.y;
    o.z = s0.z + s1.z + s2.z + s3.z + bb.z;
    o.w = s0.w + s1.w + s2.w + s3.w + bb.w;
    out4[idx] = o;
}

// ---------------------------------------------------------------------------
extern "C" void kernel_launch(void* const* d_in, const int* in_sizes, int n_in,
                              void* d_out, int out_size, void* d_ws, size_t ws_size,
                              hipStream_t stream) {
    const int*   artist = (const int*)d_in[0];
    const int*   genre  = (const int*)d_in[1];
    const float* year   = (const float*)d_in[2];
    const float* W1     = (const float*)d_in[3];
    const float* b1     = (const float*)d_in[4];
    const float* W2     = (const float*)d_in[5];
    const float* b2     = (const float*)d_in[6];
    float* out = (float*)d_out;

    char* ws = (char*)d_ws;
    uint*   H2p = (uint*)ws;                                   // 75,497,472 B
    ushort* W2b = (ushort*)(ws + 75497472);                    //  1,179,648 B
    float*  part = (float*)(ws + 75497472 + 1179648);          //  4,194,304 B

    k_prep  <<<576, 256, 0, stream>>>(W2, W2b);
    k_hidden<<<NBLK, THR, 0, stream>>>(artist, genre, year, W1, b1, H2p);
    k_gemm  <<<dim3(BATCH / 64, KSPLIT), 256, 0, stream>>>(H2p, W2b, part);
    k_reduce<<<256, 256, 0, stream>>>(part, b2, (float4*)out);
}